// Round 1
// baseline (5912.831 us; speedup 1.0000x reference)
//
#include <hip/hip_runtime.h>

#define NN 100000
#define NE 1600000
#define D 128
#define NG 1024

// ---------------- degree / norm ----------------
__global__ __launch_bounds__(256) void k_init_deg(float* __restrict__ deg) {
    int v = blockIdx.x * 256 + threadIdx.x;
    if (v < NN) deg[v] = 1.0f;   // self-loop contributes 1
}

__global__ __launch_bounds__(256) void k_count_deg(const int* __restrict__ dst,
                                                   float* __restrict__ deg) {
    int e = blockIdx.x * 256 + threadIdx.x;
    if (e < NE) atomicAdd(&deg[dst[e]], 1.0f);
}

__global__ __launch_bounds__(256) void k_dinv(float* __restrict__ deg) {
    int v = blockIdx.x * 256 + threadIdx.x;
    if (v < NN) {
        float d = deg[v];
        deg[v] = (d > 0.f) ? rsqrtf(d) : 0.f;   // overwrite in place with dinv
    }
}

// ---------------- GEMM: out[r][c] = sum_k act(in[r][k]) * W[k][c] ----------------
// act = relu(x + bias_in[k]) when relu_in != 0, else identity.
// 32-row tile, full 128 cols, W (64KB) + transposed x-tile in LDS.
// Thread tile 4 rows x 4 cols -> 16 FMA per 2 ds_read_b128 (VALU-bound).
__global__ __launch_bounds__(256) void k_gemm(const float* __restrict__ in,
                                              const float* __restrict__ W,
                                              const float* __restrict__ bias_in,
                                              int relu_in,
                                              float* __restrict__ out,
                                              int tiles_per_block) {
    __shared__ float Wl[128 * 128];       // 64 KB
    __shared__ float xt[128][36];         // transposed tile [k][m], padded (18 KB)

    int tid = threadIdx.x;
    for (int i = tid; i < 128 * 128 / 4; i += 256)
        ((float4*)Wl)[i] = ((const float4*)W)[i];

    int mloc = tid >> 3;          // 0..31  staging row
    int k0   = (tid & 7) * 16;    // 0..112 staging k-range (16 k's per thread)
    int c0   = (tid & 31) * 4;    // compute: 4 cols
    int mt   = (tid >> 5) * 4;    // compute: 4 rows

    for (int t = 0; t < tiles_per_block; ++t) {
        size_t row0 = (size_t)(blockIdx.x * tiles_per_block + t) * 32;
        __syncthreads();          // protect xt against previous-iter readers
        {
            const float* rp = in + (row0 + mloc) * D + k0;
#pragma unroll
            for (int j = 0; j < 4; ++j) {
                float4 v = *(const float4*)(rp + j * 4);
                int kk = k0 + j * 4;
                if (relu_in) {
                    v.x = fmaxf(v.x + bias_in[kk + 0], 0.f);
                    v.y = fmaxf(v.y + bias_in[kk + 1], 0.f);
                    v.z = fmaxf(v.z + bias_in[kk + 2], 0.f);
                    v.w = fmaxf(v.w + bias_in[kk + 3], 0.f);
                }
                xt[kk + 0][mloc] = v.x;
                xt[kk + 1][mloc] = v.y;
                xt[kk + 2][mloc] = v.z;
                xt[kk + 3][mloc] = v.w;
            }
        }
        __syncthreads();

        float acc[4][4] = {};
#pragma unroll
        for (int k = 0; k < 128; ++k) {
            float4 a = *(const float4*)&xt[k][mt];
            float4 w = *(const float4*)&Wl[k * D + c0];
            float av[4] = {a.x, a.y, a.z, a.w};
            float wv[4] = {w.x, w.y, w.z, w.w};
#pragma unroll
            for (int i = 0; i < 4; ++i)
#pragma unroll
                for (int j = 0; j < 4; ++j)
                    acc[i][j] += av[i] * wv[j];
        }
#pragma unroll
        for (int i = 0; i < 4; ++i) {
            float4 o = make_float4(acc[i][0], acc[i][1], acc[i][2], acc[i][3]);
            *(float4*)(out + (row0 + mt + i) * D + c0) = o;
        }
    }
}

// ---------------- agg init with self-loop: agg[v] = h[v] * dinv[v]^2 ----------------
__global__ __launch_bounds__(256) void k_selfloop(const float* __restrict__ h,
                                                  const float* __restrict__ dinv,
                                                  float* __restrict__ agg) {
    int t = blockIdx.x * 256 + threadIdx.x;   // NN*32 threads
    int v = t >> 5;
    if (v >= NN) return;
    int c = (t & 31) * 4;
    float di = dinv[v];
    float n = di * di;
    float4 x = *(const float4*)(h + (size_t)v * D + c);
    float4 o = make_float4(x.x * n, x.y * n, x.z * n, x.w * n);
    *(float4*)(agg + (size_t)v * D + c) = o;
}

// ---------------- edge scatter: agg[dst] += h[src] * dinv[src]*dinv[dst] ----------------
__global__ __launch_bounds__(256) void k_scatter(const float* __restrict__ h,
                                                 const int* __restrict__ src,
                                                 const int* __restrict__ dst,
                                                 const float* __restrict__ dinv,
                                                 float* __restrict__ agg) {
    long t = (long)blockIdx.x * 256 + threadIdx.x;   // NE*32 threads
    int e = (int)(t >> 5);
    if (e >= NE) return;
    int c = ((int)t & 31) * 4;
    int s = src[e], d = dst[e];
    float nrm = dinv[s] * dinv[d];
    float4 v = *(const float4*)(h + (size_t)s * D + c);
    float* o = agg + (size_t)d * D + c;
    atomicAdd(o + 0, v.x * nrm);
    atomicAdd(o + 1, v.y * nrm);
    atomicAdd(o + 2, v.z * nrm);
    atomicAdd(o + 3, v.w * nrm);
}

// ---------------- pooling: pooled[g] += relu(agg[v] + b2), cnt[g] += 1 ----------------
__global__ __launch_bounds__(256) void k_pool(const float* __restrict__ agg,
                                              const float* __restrict__ b2,
                                              const int* __restrict__ batch,
                                              float* __restrict__ pooled,
                                              float* __restrict__ cnt) {
    int t = blockIdx.x * 256 + threadIdx.x;   // NN*32 threads
    int v = t >> 5;
    if (v >= NN) return;
    int c = (t & 31) * 4;
    int g = batch[v];
    float4 x = *(const float4*)(agg + (size_t)v * D + c);
    float4 bb = *(const float4*)(b2 + c);
    float* o = pooled + (size_t)g * D + c;
    atomicAdd(o + 0, fmaxf(x.x + bb.x, 0.f));
    atomicAdd(o + 1, fmaxf(x.y + bb.y, 0.f));
    atomicAdd(o + 2, fmaxf(x.z + bb.z, 0.f));
    atomicAdd(o + 3, fmaxf(x.w + bb.w, 0.f));
    if ((t & 31) == 0) atomicAdd(&cnt[g], 1.0f);
}

// ---------------- classifier: out[g] = (pooled[g]/max(cnt,1)) @ Wc + bc ----------------
__global__ __launch_bounds__(64) void k_final(const float* __restrict__ pooled,
                                              const float* __restrict__ cnt,
                                              const float* __restrict__ Wc,
                                              const float* __restrict__ bc,
                                              float* __restrict__ out) {
    int g = blockIdx.x;
    int l = threadIdx.x;
    float inv = 1.0f / fmaxf(cnt[g], 1.0f);
    float p0 = pooled[(size_t)g * D + l] * inv;
    float p1 = pooled[(size_t)g * D + 64 + l] * inv;
    float s0 = p0 * Wc[l * 2 + 0] + p1 * Wc[(64 + l) * 2 + 0];
    float s1 = p0 * Wc[l * 2 + 1] + p1 * Wc[(64 + l) * 2 + 1];
    for (int off = 32; off; off >>= 1) {
        s0 += __shfl_down(s0, off);
        s1 += __shfl_down(s1, off);
    }
    if (l == 0) {
        out[g * 2 + 0] = s0 + bc[0];
        out[g * 2 + 1] = s1 + bc[1];
    }
}

extern "C" void kernel_launch(void* const* d_in, const int* in_sizes, int n_in,
                              void* d_out, int out_size, void* d_ws, size_t ws_size,
                              hipStream_t stream) {
    const float* x     = (const float*)d_in[0];
    const int*   ei    = (const int*)d_in[1];
    const int*   batch = (const int*)d_in[2];
    const float* W1    = (const float*)d_in[3];
    const float* b1    = (const float*)d_in[4];
    const float* W2    = (const float*)d_in[5];
    const float* b2    = (const float*)d_in[6];
    const float* Wc    = (const float*)d_in[7];
    const float* bc    = (const float*)d_in[8];
    float* out = (float*)d_out;

    const int* src = ei;            // edge_index[0]
    const int* dst = ei + NE;       // edge_index[1]

    float* p      = (float*)d_ws;
    float* dinv   = p;  p += 100352;                 // deg -> dinv, padded
    float* bufA   = p;  p += (size_t)NN * D;         // h1 / h2
    float* bufB   = p;  p += (size_t)NN * D;         // agg1 / agg2
    float* pooled = p;  p += (size_t)NG * D;
    float* cnt    = p;  p += NG;

    hipMemsetAsync(pooled, 0, (NG * D + NG) * sizeof(float), stream);

    k_init_deg<<<(NN + 255) / 256, 256, 0, stream>>>(dinv);
    k_count_deg<<<(NE + 255) / 256, 256, 0, stream>>>(dst, dinv);
    k_dinv<<<(NN + 255) / 256, 256, 0, stream>>>(dinv);

    // layer 1: h1 = x @ W1 ; agg1 = scatter(h1) ; (bias+relu fused into next gemm load)
    k_gemm<<<625, 256, 0, stream>>>(x, W1, nullptr, 0, bufA, 5);       // 625*5*32 = 100000 rows
    k_selfloop<<<NN * 32 / 256, 256, 0, stream>>>(bufA, dinv, bufB);
    k_scatter<<<NE * 32 / 256, 256, 0, stream>>>(bufA, src, dst, dinv, bufB);

    // layer 2: h2 = relu(agg1 + b1) @ W2 ; agg2 = scatter(h2)
    k_gemm<<<625, 256, 0, stream>>>(bufB, W2, b1, 1, bufA, 5);
    k_selfloop<<<NN * 32 / 256, 256, 0, stream>>>(bufA, dinv, bufB);
    k_scatter<<<NE * 32 / 256, 256, 0, stream>>>(bufA, src, dst, dinv, bufB);

    // pooling (bias+relu fused) + classifier
    k_pool<<<NN * 32 / 256, 256, 0, stream>>>(bufB, b2, batch, pooled, cnt);
    k_final<<<NG, 64, 0, stream>>>(pooled, cnt, Wc, bc, out);
}

// Round 2
// 834.981 us; speedup vs baseline: 7.0814x; 7.0814x over previous
//
#include <hip/hip_runtime.h>

#define NN 100000
#define NE 1600000
#define D 128
#define NG 1024
#define SCAN_CHUNK 2048
#define NB ((NN + SCAN_CHUNK - 1) / SCAN_CHUNK)   // 49

// ---------------- degree histogram (int) ----------------
__global__ __launch_bounds__(256) void k_hist(const int* __restrict__ dst,
                                              int* __restrict__ deg) {
    int e = blockIdx.x * 256 + threadIdx.x;
    if (e < NE) atomicAdd(&deg[dst[e]], 1);
}

__global__ __launch_bounds__(256) void k_dinv(const int* __restrict__ deg,
                                              float* __restrict__ dinv) {
    int v = blockIdx.x * 256 + threadIdx.x;
    if (v < NN) dinv[v] = rsqrtf((float)(deg[v] + 1));   // +1 self-loop, always >0
}

// ---------------- exclusive scan of deg -> row_ptr (3 phases) ----------------
__global__ __launch_bounds__(256) void k_scanA(const int* __restrict__ deg,
                                               int* __restrict__ row_ptr,
                                               int* __restrict__ bsum) {
    __shared__ int sh[256];
    int b = blockIdx.x, tid = threadIdx.x;
    int base = b * SCAN_CHUNK + tid * 8;
    int loc[8];
    int s = 0;
#pragma unroll
    for (int j = 0; j < 8; ++j) {
        int i = base + j;
        int d = (i < NN) ? deg[i] : 0;
        loc[j] = s;
        s += d;
    }
    sh[tid] = s;
    __syncthreads();
    for (int off = 1; off < 256; off <<= 1) {
        int v = (tid >= off) ? sh[tid - off] : 0;
        __syncthreads();
        sh[tid] += v;
        __syncthreads();
    }
    int excl = (tid == 0) ? 0 : sh[tid - 1];
#pragma unroll
    for (int j = 0; j < 8; ++j) {
        int i = base + j;
        if (i < NN) row_ptr[i] = excl + loc[j];
    }
    if (tid == 255) bsum[b] = sh[255];
}

__global__ __launch_bounds__(64) void k_scanB(int* __restrict__ bsum) {
    if (threadIdx.x == 0) {
        int run = 0;
        for (int i = 0; i < NB; ++i) {
            int t = bsum[i];
            bsum[i] = run;
            run += t;
        }
    }
}

__global__ __launch_bounds__(256) void k_scanC(int* __restrict__ row_ptr,
                                               const int* __restrict__ bsum,
                                               int* __restrict__ fill) {
    int i = blockIdx.x * 256 + threadIdx.x;
    if (i < NN) {
        int r = row_ptr[i] + bsum[i / SCAN_CHUNK];
        row_ptr[i] = r;
        fill[i] = r;
    }
    if (i == 0) row_ptr[NN] = NE;
}

// ---------------- CSR fill: csr[pos] = {src, norm} ----------------
__global__ __launch_bounds__(256) void k_fill(const int* __restrict__ src,
                                              const int* __restrict__ dst,
                                              const float* __restrict__ dinv,
                                              int* __restrict__ fill,
                                              int2* __restrict__ csr) {
    int e = blockIdx.x * 256 + threadIdx.x;
    if (e >= NE) return;
    int s = src[e], d = dst[e];
    float nrm = dinv[s] * dinv[d];
    int pos = atomicAdd(&fill[d], 1);
    csr[pos] = make_int2(s, __float_as_int(nrm));
}

// ---------------- GEMM: out[r][c] = sum_k act(in[r][k]) * W[k][c] ----------------
__global__ __launch_bounds__(256) void k_gemm(const float* __restrict__ in,
                                              const float* __restrict__ W,
                                              const float* __restrict__ bias_in,
                                              int relu_in,
                                              float* __restrict__ out,
                                              int tiles_per_block) {
    __shared__ float Wl[128 * 128];       // 64 KB
    __shared__ float xt[128][36];         // transposed tile [k][m], padded

    int tid = threadIdx.x;
    for (int i = tid; i < 128 * 128 / 4; i += 256)
        ((float4*)Wl)[i] = ((const float4*)W)[i];

    int mloc = tid >> 3;          // 0..31  staging row
    int k0   = (tid & 7) * 16;    // 0..112 staging k-range
    int c0   = (tid & 31) * 4;    // compute: 4 cols
    int mt   = (tid >> 5) * 4;    // compute: 4 rows

    for (int t = 0; t < tiles_per_block; ++t) {
        size_t row0 = (size_t)(blockIdx.x * tiles_per_block + t) * 32;
        __syncthreads();
        {
            const float* rp = in + (row0 + mloc) * D + k0;
#pragma unroll
            for (int j = 0; j < 4; ++j) {
                float4 v = *(const float4*)(rp + j * 4);
                int kk = k0 + j * 4;
                if (relu_in) {
                    v.x = fmaxf(v.x + bias_in[kk + 0], 0.f);
                    v.y = fmaxf(v.y + bias_in[kk + 1], 0.f);
                    v.z = fmaxf(v.z + bias_in[kk + 2], 0.f);
                    v.w = fmaxf(v.w + bias_in[kk + 3], 0.f);
                }
                xt[kk + 0][mloc] = v.x;
                xt[kk + 1][mloc] = v.y;
                xt[kk + 2][mloc] = v.z;
                xt[kk + 3][mloc] = v.w;
            }
        }
        __syncthreads();

        float acc[4][4] = {};
#pragma unroll
        for (int k = 0; k < 128; ++k) {
            float4 a = *(const float4*)&xt[k][mt];
            float4 w = *(const float4*)&Wl[k * D + c0];
            float av[4] = {a.x, a.y, a.z, a.w};
            float wv[4] = {w.x, w.y, w.z, w.w};
#pragma unroll
            for (int i = 0; i < 4; ++i)
#pragma unroll
                for (int j = 0; j < 4; ++j)
                    acc[i][j] += av[i] * wv[j];
        }
#pragma unroll
        for (int i = 0; i < 4; ++i) {
            float4 o = make_float4(acc[i][0], acc[i][1], acc[i][2], acc[i][3]);
            *(float4*)(out + (row0 + mt + i) * D + c0) = o;
        }
    }
}

// ---------------- gather: agg[v] = h[v]*dinv[v]^2 + sum_in h[s]*norm ----------------
__global__ __launch_bounds__(256) void k_gather(const float* __restrict__ h,
                                                const int* __restrict__ row_ptr,
                                                const int2* __restrict__ csr,
                                                const float* __restrict__ dinv,
                                                float* __restrict__ agg) {
    int t = blockIdx.x * 256 + threadIdx.x;   // NN*32 threads
    int v = t >> 5;
    if (v >= NN) return;
    int c = (t & 31) * 4;

    float di = dinv[v];
    float sl = di * di;
    float4 acc = *(const float4*)(h + (size_t)v * D + c);
    acc.x *= sl; acc.y *= sl; acc.z *= sl; acc.w *= sl;

    int p   = row_ptr[v];
    int end = row_ptr[v + 1];
    for (; p + 1 < end; p += 2) {           // 2-wide for MLP
        int2 e0 = csr[p];
        int2 e1 = csr[p + 1];
        float n0 = __int_as_float(e0.y);
        float n1 = __int_as_float(e1.y);
        float4 h0 = *(const float4*)(h + (size_t)e0.x * D + c);
        float4 h1 = *(const float4*)(h + (size_t)e1.x * D + c);
        acc.x += h0.x * n0; acc.y += h0.y * n0; acc.z += h0.z * n0; acc.w += h0.w * n0;
        acc.x += h1.x * n1; acc.y += h1.y * n1; acc.z += h1.z * n1; acc.w += h1.w * n1;
    }
    if (p < end) {
        int2 e0 = csr[p];
        float n0 = __int_as_float(e0.y);
        float4 h0 = *(const float4*)(h + (size_t)e0.x * D + c);
        acc.x += h0.x * n0; acc.y += h0.y * n0; acc.z += h0.z * n0; acc.w += h0.w * n0;
    }
    *(float4*)(agg + (size_t)v * D + c) = acc;
}

// ---------------- pooling: pooled[g] += relu(agg[v] + b2), cnt[g] += 1 ----------------
__global__ __launch_bounds__(256) void k_pool(const float* __restrict__ agg,
                                              const float* __restrict__ b2,
                                              const int* __restrict__ batch,
                                              float* __restrict__ pooled,
                                              float* __restrict__ cnt) {
    int t = blockIdx.x * 256 + threadIdx.x;
    int v = t >> 5;
    if (v >= NN) return;
    int c = (t & 31) * 4;
    int g = batch[v];
    float4 x = *(const float4*)(agg + (size_t)v * D + c);
    float4 bb = *(const float4*)(b2 + c);
    float* o = pooled + (size_t)g * D + c;
    atomicAdd(o + 0, fmaxf(x.x + bb.x, 0.f));
    atomicAdd(o + 1, fmaxf(x.y + bb.y, 0.f));
    atomicAdd(o + 2, fmaxf(x.z + bb.z, 0.f));
    atomicAdd(o + 3, fmaxf(x.w + bb.w, 0.f));
    if ((t & 31) == 0) atomicAdd(&cnt[g], 1.0f);
}

// ---------------- classifier ----------------
__global__ __launch_bounds__(64) void k_final(const float* __restrict__ pooled,
                                              const float* __restrict__ cnt,
                                              const float* __restrict__ Wc,
                                              const float* __restrict__ bc,
                                              float* __restrict__ out) {
    int g = blockIdx.x;
    int l = threadIdx.x;
    float inv = 1.0f / fmaxf(cnt[g], 1.0f);
    float p0 = pooled[(size_t)g * D + l] * inv;
    float p1 = pooled[(size_t)g * D + 64 + l] * inv;
    float s0 = p0 * Wc[l * 2 + 0] + p1 * Wc[(64 + l) * 2 + 0];
    float s1 = p0 * Wc[l * 2 + 1] + p1 * Wc[(64 + l) * 2 + 1];
    for (int off = 32; off; off >>= 1) {
        s0 += __shfl_down(s0, off);
        s1 += __shfl_down(s1, off);
    }
    if (l == 0) {
        out[g * 2 + 0] = s0 + bc[0];
        out[g * 2 + 1] = s1 + bc[1];
    }
}

extern "C" void kernel_launch(void* const* d_in, const int* in_sizes, int n_in,
                              void* d_out, int out_size, void* d_ws, size_t ws_size,
                              hipStream_t stream) {
    const float* x     = (const float*)d_in[0];
    const int*   ei    = (const int*)d_in[1];
    const int*   batch = (const int*)d_in[2];
    const float* W1    = (const float*)d_in[3];
    const float* b1    = (const float*)d_in[4];
    const float* W2    = (const float*)d_in[5];
    const float* b2    = (const float*)d_in[6];
    const float* Wc    = (const float*)d_in[7];
    const float* bc    = (const float*)d_in[8];
    float* out = (float*)d_out;

    const int* src = ei;            // edge_index[0]
    const int* dst = ei + NE;       // edge_index[1]

    char* p = (char*)d_ws;
    int*   deg_i   = (int*)p;    p += 100352 * 4;
    float* dinv    = (float*)p;  p += 100352 * 4;
    int*   row_ptr = (int*)p;    p += 100352 * 4;   // NN+1 fits
    int*   fillc   = (int*)p;    p += 100352 * 4;
    int*   bsum    = (int*)p;    p += 256 * 4;
    int2*  csr     = (int2*)p;   p += (size_t)NE * 8;
    float* bufA    = (float*)p;  p += (size_t)NN * D * 4;
    float* bufB    = (float*)p;  p += (size_t)NN * D * 4;
    float* pooled  = (float*)p;  p += NG * D * 4;
    float* cnt     = (float*)p;  p += NG * 4;

    hipMemsetAsync(deg_i, 0, 100352 * 4, stream);
    hipMemsetAsync(pooled, 0, (NG * D + NG) * 4, stream);

    // CSR build
    k_hist <<<(NE + 255) / 256, 256, 0, stream>>>(dst, deg_i);
    k_dinv <<<(NN + 255) / 256, 256, 0, stream>>>(deg_i, dinv);
    k_scanA<<<NB, 256, 0, stream>>>(deg_i, row_ptr, bsum);
    k_scanB<<<1, 64, 0, stream>>>(bsum);
    k_scanC<<<(NN + 255) / 256, 256, 0, stream>>>(row_ptr, bsum, fillc);
    k_fill <<<(NE + 255) / 256, 256, 0, stream>>>(src, dst, dinv, fillc, csr);

    // layer 1
    k_gemm  <<<625, 256, 0, stream>>>(x, W1, nullptr, 0, bufA, 5);
    k_gather<<<NN * 32 / 256 + 1, 256, 0, stream>>>(bufA, row_ptr, csr, dinv, bufB);

    // layer 2 (bias1+relu fused into gemm load)
    k_gemm  <<<625, 256, 0, stream>>>(bufB, W2, b1, 1, bufA, 5);
    k_gather<<<NN * 32 / 256 + 1, 256, 0, stream>>>(bufA, row_ptr, csr, dinv, bufB);

    // pooling (bias2+relu fused) + classifier
    k_pool <<<NN * 32 / 256 + 1, 256, 0, stream>>>(bufB, b2, batch, pooled, cnt);
    k_final<<<NG, 64, 0, stream>>>(pooled, cnt, Wc, bc, out);
}

// Round 3
// 602.932 us; speedup vs baseline: 9.8068x; 1.3849x over previous
//
#include <hip/hip_runtime.h>

#define NN 100000
#define NE 1600000
#define D 128
#define NG 1024
#define SCAN_CHUNK 2048
#define NB ((NN + SCAN_CHUNK - 1) / SCAN_CHUNK)   // 49

// ---------------- degree histogram (int) ----------------
__global__ __launch_bounds__(256) void k_hist(const int* __restrict__ dst,
                                              int* __restrict__ deg) {
    int e = blockIdx.x * 256 + threadIdx.x;
    if (e < NE) atomicAdd(&deg[dst[e]], 1);
}

__global__ __launch_bounds__(256) void k_dinv(const int* __restrict__ deg,
                                              float* __restrict__ dinv) {
    int v = blockIdx.x * 256 + threadIdx.x;
    if (v < NN) dinv[v] = rsqrtf((float)(deg[v] + 1));   // +1 self-loop, always >0
}

// ---------------- exclusive scan of deg -> row_ptr ----------------
__global__ __launch_bounds__(256) void k_scanA(const int* __restrict__ deg,
                                               int* __restrict__ row_ptr,
                                               int* __restrict__ bsum) {
    __shared__ int sh[256];
    int b = blockIdx.x, tid = threadIdx.x;
    int base = b * SCAN_CHUNK + tid * 8;
    int loc[8];
    int s = 0;
#pragma unroll
    for (int j = 0; j < 8; ++j) {
        int i = base + j;
        int d = (i < NN) ? deg[i] : 0;
        loc[j] = s;
        s += d;
    }
    sh[tid] = s;
    __syncthreads();
    for (int off = 1; off < 256; off <<= 1) {
        int v = (tid >= off) ? sh[tid - off] : 0;
        __syncthreads();
        sh[tid] += v;
        __syncthreads();
    }
    int excl = (tid == 0) ? 0 : sh[tid - 1];
#pragma unroll
    for (int j = 0; j < 8; ++j) {
        int i = base + j;
        if (i < NN) row_ptr[i] = excl + loc[j];
    }
    if (tid == 255) bsum[b] = sh[255];
}

__global__ __launch_bounds__(64) void k_scanB(int* __restrict__ bsum) {
    if (threadIdx.x == 0) {
        int run = 0;
        for (int i = 0; i < NB; ++i) {
            int t = bsum[i];
            bsum[i] = run;
            run += t;
        }
    }
}

__global__ __launch_bounds__(256) void k_scanC(int* __restrict__ row_ptr,
                                               const int* __restrict__ bsum,
                                               int* __restrict__ fill) {
    int i = blockIdx.x * 256 + threadIdx.x;
    if (i < NN) {
        int r = row_ptr[i] + bsum[i / SCAN_CHUNK];
        row_ptr[i] = r;
        fill[i] = r;
    }
    if (i == 0) row_ptr[NN] = NE;
}

// ---------------- CSR fill: csr[pos] = {src, norm} ----------------
__global__ __launch_bounds__(256) void k_fill(const int* __restrict__ src,
                                              const int* __restrict__ dst,
                                              const float* __restrict__ dinv,
                                              int* __restrict__ fill,
                                              int2* __restrict__ csr) {
    int e = blockIdx.x * 256 + threadIdx.x;
    if (e >= NE) return;
    int s = src[e], d = dst[e];
    float nrm = dinv[s] * dinv[d];
    int pos = atomicAdd(&fill[d], 1);
    csr[pos] = make_int2(s, __float_as_int(nrm));
}

// ---------------- graph boundaries from sorted batch ----------------
__global__ __launch_bounds__(256) void k_bounds(const int* __restrict__ batch,
                                                int* __restrict__ gstart) {
    int g = blockIdx.x * 256 + threadIdx.x;
    if (g > NG) return;
    if (g == NG) { gstart[NG] = NN; return; }
    int lo = 0, hi = NN;               // first v with batch[v] >= g
    while (lo < hi) {
        int mid = (lo + hi) >> 1;
        if (batch[mid] < g) lo = mid + 1; else hi = mid;
    }
    gstart[g] = lo;
}

// ---------------- GEMM: out[r][c] = sum_k act(in[r][k]) * W[k][c] ----------------
__global__ __launch_bounds__(256) void k_gemm(const float* __restrict__ in,
                                              const float* __restrict__ W,
                                              const float* __restrict__ bias_in,
                                              int relu_in,
                                              float* __restrict__ out,
                                              int tiles_per_block) {
    __shared__ float Wl[128 * 128];       // 64 KB
    __shared__ float xt[128][36];         // transposed tile [k][m], padded

    int tid = threadIdx.x;
    for (int i = tid; i < 128 * 128 / 4; i += 256)
        ((float4*)Wl)[i] = ((const float4*)W)[i];

    int mloc = tid >> 3;          // 0..31  staging row
    int k0   = (tid & 7) * 16;    // 0..112 staging k-range
    int c0   = (tid & 31) * 4;    // compute: 4 cols
    int mt   = (tid >> 5) * 4;    // compute: 4 rows

    for (int t = 0; t < tiles_per_block; ++t) {
        size_t row0 = (size_t)(blockIdx.x * tiles_per_block + t) * 32;
        __syncthreads();
        {
            const float* rp = in + (row0 + mloc) * D + k0;
#pragma unroll
            for (int j = 0; j < 4; ++j) {
                float4 v = *(const float4*)(rp + j * 4);
                int kk = k0 + j * 4;
                if (relu_in) {
                    v.x = fmaxf(v.x + bias_in[kk + 0], 0.f);
                    v.y = fmaxf(v.y + bias_in[kk + 1], 0.f);
                    v.z = fmaxf(v.z + bias_in[kk + 2], 0.f);
                    v.w = fmaxf(v.w + bias_in[kk + 3], 0.f);
                }
                xt[kk + 0][mloc] = v.x;
                xt[kk + 1][mloc] = v.y;
                xt[kk + 2][mloc] = v.z;
                xt[kk + 3][mloc] = v.w;
            }
        }
        __syncthreads();

        float acc[4][4] = {};
#pragma unroll
        for (int k = 0; k < 128; ++k) {
            float4 a = *(const float4*)&xt[k][mt];
            float4 w = *(const float4*)&Wl[k * D + c0];
            float av[4] = {a.x, a.y, a.z, a.w};
            float wv[4] = {w.x, w.y, w.z, w.w};
#pragma unroll
            for (int i = 0; i < 4; ++i)
#pragma unroll
                for (int j = 0; j < 4; ++j)
                    acc[i][j] += av[i] * wv[j];
        }
#pragma unroll
        for (int i = 0; i < 4; ++i) {
            float4 o = make_float4(acc[i][0], acc[i][1], acc[i][2], acc[i][3]);
            *(float4*)(out + (row0 + mt + i) * D + c0) = o;
        }
    }
}

// ---------------- gather: agg[v] = h[v]*dinv[v]^2 + sum_in h[s]*norm ----------------
__global__ __launch_bounds__(256) void k_gather(const float* __restrict__ h,
                                                const int* __restrict__ row_ptr,
                                                const int2* __restrict__ csr,
                                                const float* __restrict__ dinv,
                                                float* __restrict__ agg) {
    int t = blockIdx.x * 256 + threadIdx.x;   // NN*32 threads
    int v = t >> 5;
    if (v >= NN) return;
    int c = (t & 31) * 4;

    float di = dinv[v];
    float sl = di * di;
    float4 acc = *(const float4*)(h + (size_t)v * D + c);
    acc.x *= sl; acc.y *= sl; acc.z *= sl; acc.w *= sl;

    int p   = row_ptr[v];
    int end = row_ptr[v + 1];
    for (; p + 1 < end; p += 2) {           // 2-wide for MLP
        int2 e0 = csr[p];
        int2 e1 = csr[p + 1];
        float n0 = __int_as_float(e0.y);
        float n1 = __int_as_float(e1.y);
        float4 h0 = *(const float4*)(h + (size_t)e0.x * D + c);
        float4 h1 = *(const float4*)(h + (size_t)e1.x * D + c);
        acc.x += h0.x * n0; acc.y += h0.y * n0; acc.z += h0.z * n0; acc.w += h0.w * n0;
        acc.x += h1.x * n1; acc.y += h1.y * n1; acc.z += h1.z * n1; acc.w += h1.w * n1;
    }
    if (p < end) {
        int2 e0 = csr[p];
        float n0 = __int_as_float(e0.y);
        float4 h0 = *(const float4*)(h + (size_t)e0.x * D + c);
        acc.x += h0.x * n0; acc.y += h0.y * n0; acc.z += h0.z * n0; acc.w += h0.w * n0;
    }
    *(float4*)(agg + (size_t)v * D + c) = acc;
}

// ---------------- fused pool + classifier (block per graph) ----------------
__global__ __launch_bounds__(128) void k_poolcls(const float* __restrict__ agg,
                                                 const float* __restrict__ b2,
                                                 const int* __restrict__ gstart,
                                                 const float* __restrict__ Wc,
                                                 const float* __restrict__ bc,
                                                 float* __restrict__ out) {
    int g = blockIdx.x;
    int c = threadIdx.x;
    int v0 = gstart[g], v1 = gstart[g + 1];
    float bb = b2[c];
    float acc = 0.f;
    int v = v0;
    for (; v + 3 < v1; v += 4) {            // 4-wide unroll for ILP
        float x0 = agg[(size_t)(v + 0) * D + c];
        float x1 = agg[(size_t)(v + 1) * D + c];
        float x2 = agg[(size_t)(v + 2) * D + c];
        float x3 = agg[(size_t)(v + 3) * D + c];
        acc += fmaxf(x0 + bb, 0.f) + fmaxf(x1 + bb, 0.f)
             + fmaxf(x2 + bb, 0.f) + fmaxf(x3 + bb, 0.f);
    }
    for (; v < v1; ++v)
        acc += fmaxf(agg[(size_t)v * D + c] + bb, 0.f);

    float inv = 1.0f / fmaxf((float)(v1 - v0), 1.0f);
    float pv = acc * inv;

    __shared__ float red[2][128];
    red[0][c] = pv * Wc[c * 2 + 0];
    red[1][c] = pv * Wc[c * 2 + 1];
    __syncthreads();
    if (c < 64) {
        float s = red[0][c] + red[0][c + 64];
        for (int off = 32; off; off >>= 1) s += __shfl_down(s, off);
        if (c == 0) out[g * 2 + 0] = s + bc[0];
    } else {
        int l = c - 64;
        float s = red[1][l] + red[1][l + 64];
        for (int off = 32; off; off >>= 1) s += __shfl_down(s, off);
        if (l == 0) out[g * 2 + 1] = s + bc[1];
    }
}

extern "C" void kernel_launch(void* const* d_in, const int* in_sizes, int n_in,
                              void* d_out, int out_size, void* d_ws, size_t ws_size,
                              hipStream_t stream) {
    const float* x     = (const float*)d_in[0];
    const int*   ei    = (const int*)d_in[1];
    const int*   batch = (const int*)d_in[2];
    const float* W1    = (const float*)d_in[3];
    const float* b1    = (const float*)d_in[4];
    const float* W2    = (const float*)d_in[5];
    const float* b2    = (const float*)d_in[6];
    const float* Wc    = (const float*)d_in[7];
    const float* bc    = (const float*)d_in[8];
    float* out = (float*)d_out;

    const int* src = ei;            // edge_index[0]
    const int* dst = ei + NE;       // edge_index[1]

    char* p = (char*)d_ws;
    int*   deg_i   = (int*)p;    p += 100352 * 4;
    float* dinv    = (float*)p;  p += 100352 * 4;
    int*   row_ptr = (int*)p;    p += 100352 * 4;   // NN+1 fits
    int*   fillc   = (int*)p;    p += 100352 * 4;
    int*   bsum    = (int*)p;    p += 256 * 4;
    int*   gstart  = (int*)p;    p += 1056 * 4;     // NG+1
    int2*  csr     = (int2*)p;   p += (size_t)NE * 8;
    float* bufA    = (float*)p;  p += (size_t)NN * D * 4;
    float* bufB    = (float*)p;  p += (size_t)NN * D * 4;

    hipMemsetAsync(deg_i, 0, 100352 * 4, stream);

    // CSR build + graph bounds
    k_hist  <<<(NE + 255) / 256, 256, 0, stream>>>(dst, deg_i);
    k_dinv  <<<(NN + 255) / 256, 256, 0, stream>>>(deg_i, dinv);
    k_scanA <<<NB, 256, 0, stream>>>(deg_i, row_ptr, bsum);
    k_scanB <<<1, 64, 0, stream>>>(bsum);
    k_scanC <<<(NN + 255) / 256, 256, 0, stream>>>(row_ptr, bsum, fillc);
    k_fill  <<<(NE + 255) / 256, 256, 0, stream>>>(src, dst, dinv, fillc, csr);
    k_bounds<<<(NG + 256) / 256, 256, 0, stream>>>(batch, gstart);

    // layer 1
    k_gemm  <<<625, 256, 0, stream>>>(x, W1, nullptr, 0, bufA, 5);
    k_gather<<<NN * 32 / 256 + 1, 256, 0, stream>>>(bufA, row_ptr, csr, dinv, bufB);

    // layer 2 (bias1+relu fused into gemm load)
    k_gemm  <<<625, 256, 0, stream>>>(bufB, W2, b1, 1, bufA, 5);
    k_gather<<<NN * 32 / 256 + 1, 256, 0, stream>>>(bufA, row_ptr, csr, dinv, bufB);

    // fused pooling (bias2+relu) + classifier
    k_poolcls<<<NG, 128, 0, stream>>>(bufB, b2, gstart, Wc, bc, out);
}